// Round 1
// baseline (848.237 us; speedup 1.0000x reference)
//
#include <hip/hip_runtime.h>

// Problem constants (from reference)
#define B_TOTAL 262144
#define E_NUM   100000
#define SD      64
#define TD      64
#define FD      128   // S_DIM + T_DIM
#define NCYCLE  30

// One wavefront (64 lanes) per batch element; lane = dim index d in [0,64).
// Every gather of a 64-float table row is fully coalesced (256B per wave load).
// Lane d accumulates score contributions for feature j=d (static half) and
// j=64+d (temporal half), then a 6-step shfl_xor reduction sums the wave.

__device__ __forceinline__ float time_emb(const float* __restrict__ A,
                                          const float* __restrict__ F,
                                          const float* __restrict__ P,
                                          int base, int kstride,
                                          float tv0, float tv1, float tv2)
{
    float s;
    s  = A[base]             * sinf(F[base]             * tv0 + P[base]);
    s += A[base + kstride]   * sinf(F[base + kstride]   * tv1 + P[base + kstride]);
    s += A[base + 2*kstride] * sinf(F[base + 2*kstride] * tv2 + P[base + 2*kstride]);
    return s;
}

__global__ __launch_bounds__(256) void desimple_score(
    const int*   __restrict__ heads,
    const int*   __restrict__ rels,
    const int*   __restrict__ tails,
    const float* __restrict__ years,
    const float* __restrict__ months,
    const float* __restrict__ days,
    const int*   __restrict__ date_ids,
    const float* __restrict__ ent_h,
    const float* __restrict__ ent_t,
    const float* __restrict__ rel_f,
    const float* __restrict__ rel_i,
    const float* __restrict__ stw,
    const float* __restrict__ rtc,
    const float* __restrict__ amps_h,
    const float* __restrict__ freq_h,
    const float* __restrict__ phi_h,
    const float* __restrict__ amps_t,
    const float* __restrict__ freq_t,
    const float* __restrict__ phi_t,
    float* __restrict__ out)
{
    const int lane = threadIdx.x & 63;
    const int b = blockIdx.x * (blockDim.x >> 6) + (threadIdx.x >> 6);
    if (b >= B_TOTAL) return;

    // Wave-uniform scalars (broadcast loads)
    const int   h   = heads[b];
    const int   r   = rels[b];
    const int   t   = tails[b];
    const int   did = date_ids[b];
    const float tv0 = years[b];
    const float tv1 = months[b];
    const float tv2 = days[b];

    const int d = lane;
    const int KS = E_NUM * TD;   // k-slice stride of amps/freq/phi (6.4M floats)

    // shared temporal window (added to all four time embeddings)
    const float sw = stw[(did / NCYCLE) * TD + d];

    const int baseH = h * TD + d;
    const int baseT = t * TD + d;

    // four time embeddings (each already excludes sw; added below)
    const float teHh = time_emb(amps_h, freq_h, phi_h, baseH, KS, tv0, tv1, tv2) + sw;
    const float teTt = time_emb(amps_t, freq_t, phi_t, baseT, KS, tv0, tv1, tv2) + sw;
    const float teHt = time_emb(amps_h, freq_h, phi_h, baseT, KS, tv0, tv1, tv2) + sw;
    const float teTh = time_emb(amps_t, freq_t, phi_t, baseH, KS, tv0, tv1, tv2) + sw;

    // relation features modulated by date features: r' = r * (1 + rtc[did])
    const int rb  = r * FD + d;
    const int db  = did * FD + d;
    const float time_s = rtc[db];
    const float time_t = rtc[db + 64];
    const float r1s = rel_f[rb]      * (1.0f + time_s);
    const float r1t = rel_f[rb + 64] * (1.0f + time_t);
    const float r2s = rel_i[rb]      * (1.0f + time_s);
    const float r2t = rel_i[rb + 64] * (1.0f + time_t);

    // static entity features
    const float ehH = ent_h[h * SD + d];
    const float ehT = ent_h[t * SD + d];
    const float etT = ent_t[t * SD + d];
    const float etH = ent_t[h * SD + d];

    // score contribution for feature j=d (static) and j=64+d (temporal)
    float contrib = ehH * r1s * etT      // h1*r1*t1, static half
                  + teHh * r1t * teTt    // h1*r1*t1, temporal half
                  + ehT * r2s * etH      // h2*r2*t2, static half
                  + teHt * r2t * teTh;   // h2*r2*t2, temporal half

    // wave reduction over 64 lanes
    #pragma unroll
    for (int off = 32; off > 0; off >>= 1)
        contrib += __shfl_xor(contrib, off, 64);

    if (lane == 0)
        out[b] = 0.5f * contrib;
}

extern "C" void kernel_launch(void* const* d_in, const int* in_sizes, int n_in,
                              void* d_out, int out_size, void* d_ws, size_t ws_size,
                              hipStream_t stream) {
    const int*   heads    = (const int*)  d_in[0];
    const int*   rels     = (const int*)  d_in[1];
    const int*   tails    = (const int*)  d_in[2];
    const float* years    = (const float*)d_in[3];
    const float* months   = (const float*)d_in[4];
    const float* days     = (const float*)d_in[5];
    const int*   date_ids = (const int*)  d_in[6];
    const float* ent_h    = (const float*)d_in[7];
    const float* ent_t    = (const float*)d_in[8];
    const float* rel_f    = (const float*)d_in[9];
    const float* rel_i    = (const float*)d_in[10];
    const float* stw      = (const float*)d_in[11];
    const float* rtc      = (const float*)d_in[12];
    const float* amps_h   = (const float*)d_in[13];
    const float* freq_h   = (const float*)d_in[14];
    const float* phi_h    = (const float*)d_in[15];
    const float* amps_t   = (const float*)d_in[16];
    const float* freq_t   = (const float*)d_in[17];
    const float* phi_t    = (const float*)d_in[18];
    float* out = (float*)d_out;

    const int threads = 256;                    // 4 waves/block
    const int waves_per_block = threads / 64;
    const int blocks = B_TOTAL / waves_per_block; // 65536

    desimple_score<<<blocks, threads, 0, stream>>>(
        heads, rels, tails, years, months, days, date_ids,
        ent_h, ent_t, rel_f, rel_i, stw, rtc,
        amps_h, freq_h, phi_h, amps_t, freq_t, phi_t, out);
}

// Round 2
// 744.237 us; speedup vs baseline: 1.1397x; 1.1397x over previous
//
#include <hip/hip_runtime.h>

// Problem constants (from reference)
#define B_TOTAL 262144
#define E_NUM   100000
#define SD      64
#define TD      64
#define FD      128   // S_DIM + T_DIM
#define NCYCLE  30

// One wavefront (64 lanes) per batch element; lane = dim index d in [0,64).
// Every gather of a 64-float table row is fully coalesced (256B per wave load).
//
// Round-2 structure: ALL ~47 independent global loads are issued first (loads
// into named registers, no compute interleaved), then the math phase runs on
// __sinf (native v_sin_f32 path). __launch_bounds__(256,4) gives the register
// allocator budget (<=128 VGPR) to keep the full load batch in flight.

__global__ __launch_bounds__(256, 4) void desimple_score(
    const int*   __restrict__ heads,
    const int*   __restrict__ rels,
    const int*   __restrict__ tails,
    const float* __restrict__ years,
    const float* __restrict__ months,
    const float* __restrict__ days,
    const int*   __restrict__ date_ids,
    const float* __restrict__ ent_h,
    const float* __restrict__ ent_t,
    const float* __restrict__ rel_f,
    const float* __restrict__ rel_i,
    const float* __restrict__ stw,
    const float* __restrict__ rtc,
    const float* __restrict__ amps_h,
    const float* __restrict__ freq_h,
    const float* __restrict__ phi_h,
    const float* __restrict__ amps_t,
    const float* __restrict__ freq_t,
    const float* __restrict__ phi_t,
    float* __restrict__ out)
{
    const int lane = threadIdx.x & 63;
    const int b = blockIdx.x * (blockDim.x >> 6) + (threadIdx.x >> 6);

    // Wave-uniform scalars (broadcast loads)
    const int   h   = heads[b];
    const int   r   = rels[b];
    const int   t   = tails[b];
    const int   did = date_ids[b];
    const float tv0 = years[b];
    const float tv1 = months[b];
    const float tv2 = days[b];

    const int d  = lane;
    const int KS = E_NUM * TD;   // harmonic stride in amps/freq/phi

    const int baseH = h * TD + d;
    const int baseT = t * TD + d;
    const int rb    = r * FD + d;
    const int db    = did * FD + d;

    // ---------------- LOAD PHASE: all independent gathers issued up front ----
    // time-emb tables at head entity (h-tables and t-tables)
    float AHh0 = amps_h[baseH];          float AHh1 = amps_h[baseH + KS];     float AHh2 = amps_h[baseH + 2*KS];
    float FHh0 = freq_h[baseH];          float FHh1 = freq_h[baseH + KS];     float FHh2 = freq_h[baseH + 2*KS];
    float PHh0 = phi_h [baseH];          float PHh1 = phi_h [baseH + KS];     float PHh2 = phi_h [baseH + 2*KS];
    float ATh0 = amps_t[baseH];          float ATh1 = amps_t[baseH + KS];     float ATh2 = amps_t[baseH + 2*KS];
    float FTh0 = freq_t[baseH];          float FTh1 = freq_t[baseH + KS];     float FTh2 = freq_t[baseH + 2*KS];
    float PTh0 = phi_t [baseH];          float PTh1 = phi_t [baseH + KS];     float PTh2 = phi_t [baseH + 2*KS];
    // time-emb tables at tail entity
    float AHt0 = amps_h[baseT];          float AHt1 = amps_h[baseT + KS];     float AHt2 = amps_h[baseT + 2*KS];
    float FHt0 = freq_h[baseT];          float FHt1 = freq_h[baseT + KS];     float FHt2 = freq_h[baseT + 2*KS];
    float PHt0 = phi_h [baseT];          float PHt1 = phi_h [baseT + KS];     float PHt2 = phi_h [baseT + 2*KS];
    float ATt0 = amps_t[baseT];          float ATt1 = amps_t[baseT + KS];     float ATt2 = amps_t[baseT + 2*KS];
    float FTt0 = freq_t[baseT];          float FTt1 = freq_t[baseT + KS];     float FTt2 = freq_t[baseT + 2*KS];
    float PTt0 = phi_t [baseT];          float PTt1 = phi_t [baseT + KS];     float PTt2 = phi_t [baseT + 2*KS];
    // static entity features
    float ehH = ent_h[h * SD + d];
    float ehT = ent_h[t * SD + d];
    float etT = ent_t[t * SD + d];
    float etH = ent_t[h * SD + d];
    // relation + date features (small tables, L2-resident)
    float rf_s = rel_f[rb];              float rf_t = rel_f[rb + 64];
    float ri_s = rel_i[rb];              float ri_t = rel_i[rb + 64];
    float tm_s = rtc[db];                float tm_t = rtc[db + 64];
    float sw   = stw[(did / NCYCLE) * TD + d];

    // ---------------- COMPUTE PHASE ------------------------------------------
    // four time embeddings: sum_k a_k * sin(f_k*tv_k + p_k), + shared window
    float teHh = AHh0 * __sinf(FHh0 * tv0 + PHh0)
               + AHh1 * __sinf(FHh1 * tv1 + PHh1)
               + AHh2 * __sinf(FHh2 * tv2 + PHh2) + sw;
    float teTh = ATh0 * __sinf(FTh0 * tv0 + PTh0)
               + ATh1 * __sinf(FTh1 * tv1 + PTh1)
               + ATh2 * __sinf(FTh2 * tv2 + PTh2) + sw;
    float teHt = AHt0 * __sinf(FHt0 * tv0 + PHt0)
               + AHt1 * __sinf(FHt1 * tv1 + PHt1)
               + AHt2 * __sinf(FHt2 * tv2 + PHt2) + sw;
    float teTt = ATt0 * __sinf(FTt0 * tv0 + PTt0)
               + ATt1 * __sinf(FTt1 * tv1 + PTt1)
               + ATt2 * __sinf(FTt2 * tv2 + PTt2) + sw;

    // relation features modulated by date features: r' = r * (1 + rtc[did])
    const float r1s = rf_s * (1.0f + tm_s);
    const float r1t = rf_t * (1.0f + tm_t);
    const float r2s = ri_s * (1.0f + tm_s);
    const float r2t = ri_t * (1.0f + tm_t);

    // score contribution for feature j=d (static) and j=64+d (temporal)
    float contrib = ehH * r1s * etT      // h1*r1*t1, static half
                  + teHh * r1t * teTt    // h1*r1*t1, temporal half
                  + ehT * r2s * etH      // h2*r2*t2, static half
                  + teHt * r2t * teTh;   // h2*r2*t2, temporal half

    // wave reduction over 64 lanes
    #pragma unroll
    for (int off = 32; off > 0; off >>= 1)
        contrib += __shfl_xor(contrib, off, 64);

    if (lane == 0)
        out[b] = 0.5f * contrib;
}

extern "C" void kernel_launch(void* const* d_in, const int* in_sizes, int n_in,
                              void* d_out, int out_size, void* d_ws, size_t ws_size,
                              hipStream_t stream) {
    const int*   heads    = (const int*)  d_in[0];
    const int*   rels     = (const int*)  d_in[1];
    const int*   tails    = (const int*)  d_in[2];
    const float* years    = (const float*)d_in[3];
    const float* months   = (const float*)d_in[4];
    const float* days     = (const float*)d_in[5];
    const int*   date_ids = (const int*)  d_in[6];
    const float* ent_h    = (const float*)d_in[7];
    const float* ent_t    = (const float*)d_in[8];
    const float* rel_f    = (const float*)d_in[9];
    const float* rel_i    = (const float*)d_in[10];
    const float* stw      = (const float*)d_in[11];
    const float* rtc      = (const float*)d_in[12];
    const float* amps_h   = (const float*)d_in[13];
    const float* freq_h   = (const float*)d_in[14];
    const float* phi_h    = (const float*)d_in[15];
    const float* amps_t   = (const float*)d_in[16];
    const float* freq_t   = (const float*)d_in[17];
    const float* phi_t    = (const float*)d_in[18];
    float* out = (float*)d_out;

    const int threads = 256;                      // 4 waves/block
    const int waves_per_block = threads / 64;
    const int blocks = B_TOTAL / waves_per_block; // 65536 (divides exactly)

    desimple_score<<<blocks, threads, 0, stream>>>(
        heads, rels, tails, years, months, days, date_ids,
        ent_h, ent_t, rel_f, rel_i, stw, rtc,
        amps_h, freq_h, phi_h, amps_t, freq_t, phi_t, out);
}